// Round 11
// baseline (734.963 us; speedup 1.0000x reference)
//
#include <hip/hip_runtime.h>
#include <hip/hip_cooperative_groups.h>

namespace cg = cooperative_groups;

#define N_NODES 20000
#define N_EDGES 640000
#define DIM 128
#define NGRAPH 64
#define NBUCK 313          // ceil(20000/64) dst buckets of 64 nodes
#define EPB 2048           // edges per histogram/partition chunk
#define NB_HIST 313
#define NB_WCONV 32
#define GRID 1024          // 4 blocks/CU x 256 CUs
#define NZERO 443          // 313 ghist + 2 tickets + 64 gsum + 64 gcnt
#define RED_BLOCKS 512

typedef __attribute__((ext_vector_type(8))) short short8;
typedef __attribute__((ext_vector_type(4))) float floatx4;

__device__ __forceinline__ unsigned int bf16rne(float f) {
    unsigned int u = __float_as_uint(f);
    return (u + 0x7FFFu + ((u >> 16) & 1u)) >> 16;
}

// LDS union: max member = partition (21392 B) -> LDS no longer the coop limiter
union SMemU {
    struct { int lhist[NBUCK], lbase[NBUCK], gbase[NBUCK], lcur[NBUCK]; int2 lrec[EPB]; } p;
    struct { unsigned short h[32 * DIM], l[32 * DIM]; } g;   // 8 KB + 8 KB
    struct { int nh[64], ncur[64]; } s;
    struct { float sbin[NGRAPH]; int cbin[NGRAPH]; } rd;
};

__global__ __launch_bounds__(256, 4) void mega(
    const int* __restrict__ srcA, const int* __restrict__ dstA,
    const float* __restrict__ ew, const int* __restrict__ batch,
    const float* __restrict__ x,
    const float* __restrict__ W1rel, const float* __restrict__ b1,
    const float* __restrict__ W1root,
    const float* __restrict__ W3rel, const float* __restrict__ b3,
    const float* __restrict__ W3root,
    const float* __restrict__ Wlin, const float* __restrict__ blin,
    unsigned short* __restrict__ wbh, unsigned short* __restrict__ wbl,
    unsigned short* __restrict__ yb, float* __restrict__ r,
    int* __restrict__ zr, int* __restrict__ boff, int* __restrict__ gcursor,
    int2* __restrict__ part, int2* __restrict__ sorted, int* __restrict__ off,
    float* __restrict__ aArr, float* __restrict__ bArr,
    float* __restrict__ vrel, float* __restrict__ vroot, float* __restrict__ cb3,
    float* __restrict__ out)
{
    __shared__ SMemU sm;
    __shared__ int flag;
    cg::grid_group grid = cg::this_grid();
    const int t = threadIdx.x;
    const int B = blockIdx.x;
    const int G = gridDim.x;

    int* ghist = zr;
    int* ticket_hist = zr + 313;
    int* ticket_red = zr + 314;
    float* gsum = (float*)(zr + 315);
    int* gcntg = zr + 379;

    // ---------------- Pz: zero comm buffers ----------------
    for (int i = B * 256 + t; i < NZERO; i += G * 256) zr[i] = 0;
    grid.sync();

    // ---------------- P0: hist(+scan) | wconv | params ----------------
    for (int job = B; job < NB_HIST + NB_WCONV + 1; job += G) {
        if (job < NB_HIST) {
            for (int i = t; i < NBUCK; i += 256) sm.p.lhist[i] = 0;
            __syncthreads();
            const int e0 = job * EPB;
            for (int i = 0; i < 8; ++i) {
                int e = e0 + i * 256 + t;
                if (e < N_EDGES) atomicAdd(&sm.p.lhist[dstA[e] >> 6], 1);
            }
            __syncthreads();
            for (int i = t; i < NBUCK; i += 256)
                if (sm.p.lhist[i]) atomicAdd(&ghist[i], sm.p.lhist[i]);
            __syncthreads();
            if (t == 0) {
                __threadfence();
                flag = (atomicAdd(ticket_hist, 1) == NB_HIST - 1);
            }
            __syncthreads();
            if (flag && t < 64) {
                int carry = 0;
                for (int c = 0; c < 5; ++c) {
                    int idx = c * 64 + t;
                    int v = (idx < NBUCK)
                        ? __hip_atomic_load(&ghist[idx], __ATOMIC_RELAXED,
                                            __HIP_MEMORY_SCOPE_AGENT)
                        : 0;
                    int xv = v;
                    for (int s = 1; s < 64; s <<= 1) {
                        int u = __shfl_up(xv, s);
                        if (t >= s) xv += u;
                    }
                    int excl = carry + xv - v;
                    if (idx < NBUCK) { boff[idx] = excl; gcursor[idx] = excl; }
                    carry += __shfl(xv, 63);
                }
                if (t == 0) boff[NBUCK] = carry;
                __threadfence();
            }
        } else if (job < NB_HIST + NB_WCONV) {
            const int bb = job - NB_HIST;
            for (int i = bb * 256 + t; i < 256 * DIM; i += NB_WCONV * 256) {
                int n = i >> 7, k = i & 127;
                float v = (n < DIM) ? W1rel[n * DIM + k] : W1root[(n - DIM) * DIM + k];
                unsigned int h = bf16rne(v);
                wbh[i] = (unsigned short)h;
                wbl[i] = (unsigned short)bf16rne(v - __uint_as_float(h << 16));
            }
        } else {
            if (t < 64) {
                for (int kk = 0; kk < 2; ++kk) {
                    int k = t + kk * 64;
                    float sr = 0.f, so = 0.f;
                    for (int h = 0; h < DIM; ++h) {
                        float wl = Wlin[h];
                        sr = fmaf(wl, W3rel[h * DIM + k], sr);
                        so = fmaf(wl, W3root[h * DIM + k], so);
                    }
                    vrel[k] = sr;
                    vroot[k] = so;
                }
                float c = b3[t] * Wlin[t] + b3[t + 64] * Wlin[t + 64];
                for (int m = 32; m > 0; m >>= 1) c += __shfl_xor(c, m);
                if (t == 0) cb3[0] = c;
            }
        }
        __syncthreads();
    }
    grid.sync();

    // ---------------- P1: partition | gemm (32-col tiles) ----------------
    for (int job = B; job < NB_HIST + 2504; job += G) {
        if (job < NB_HIST) {
            for (int i = t; i < NBUCK; i += 256) sm.p.lhist[i] = 0;
            __syncthreads();
            const int e0 = job * EPB;
            const int tot = min(EPB, N_EDGES - e0);
            int mys[8], myd[8];
            float myw[8];
            for (int i = 0; i < 8; ++i) {
                int e = e0 + i * 256 + t;
                if (e < N_EDGES) {
                    mys[i] = srcA[e];
                    myd[i] = dstA[e];
                    myw[i] = ew[e];
                    atomicAdd(&sm.p.lhist[myd[i] >> 6], 1);
                } else {
                    myd[i] = -1;
                }
            }
            __syncthreads();
            if (t < 64) {
                int carry = 0;
                for (int c = 0; c < 5; ++c) {
                    int idx = c * 64 + t;
                    int v = (idx < NBUCK) ? sm.p.lhist[idx] : 0;
                    int xv = v;
                    for (int s = 1; s < 64; s <<= 1) {
                        int u = __shfl_up(xv, s);
                        if (t >= s) xv += u;
                    }
                    if (idx < NBUCK) { sm.p.lbase[idx] = carry + xv - v; sm.p.lcur[idx] = 0; }
                    carry += __shfl(xv, 63);
                }
            }
            __syncthreads();
            for (int i = t; i < NBUCK; i += 256) {
                int cnt = sm.p.lhist[i];
                sm.p.gbase[i] = cnt ? atomicAdd(&gcursor[i], cnt) : 0;
            }
            __syncthreads();
            for (int i = 0; i < 8; ++i) {
                if (myd[i] >= 0) {
                    int bb = myd[i] >> 6;
                    int slot = sm.p.lbase[bb] + atomicAdd(&sm.p.lcur[bb], 1);
                    sm.p.lrec[slot] = make_int2((myd[i] << 16) | mys[i], __float_as_int(myw[i]));
                }
            }
            __syncthreads();
            for (int i = t; i < tot; i += 256) {
                int2 rc = sm.p.lrec[i];
                int bb = ((unsigned)rc.x >> 16) >> 6;
                part[sm.p.gbase[bb] + (i - sm.p.lbase[bb])] = rc;
            }
        } else {
            // gemm 64-row x 32-col tile
            const int tile = job - NB_HIST;
            const int g = tile >> 3;
            const int col0 = (tile & 7) * 32;
            uint4* sh4 = (uint4*)sm.g.h;
            uint4* sl4 = (uint4*)sm.g.l;
            const uint4* gh = (const uint4*)wbh + (size_t)col0 * 16;
            const uint4* gl = (const uint4*)wbl + (size_t)col0 * 16;
            for (int i = t; i < 512; i += 256) {
                int row = i >> 4, c = i & 15;
                int sc = row * 16 + (c ^ (row & 15));
                sh4[sc] = gh[i];
                sl4[sc] = gl[i];
            }
            __syncthreads();
            const int lane = t & 63;
            const int m = lane & 15;
            const int q = lane >> 4;
            const int row0 = g * 64 + (t >> 6) * 16;
            const int row = row0 + m;
            const bool ok = row < N_NODES;
            const short8* SH = (const short8*)sm.g.h;
            const short8* SL = (const short8*)sm.g.l;
            floatx4 acc[2];
            acc[0] = (floatx4)(0.f);
            acc[1] = (floatx4)(0.f);
            #pragma unroll
            for (int kc = 0; kc < 4; ++kc) {
                float4 v0 = make_float4(0.f, 0.f, 0.f, 0.f);
                float4 v1 = make_float4(0.f, 0.f, 0.f, 0.f);
                if (ok) {
                    const float4* xp = (const float4*)(x + (size_t)row * DIM + kc * 32 + q * 8);
                    v0 = xp[0];
                    v1 = xp[1];
                }
                float f[8] = {v0.x, v0.y, v0.z, v0.w, v1.x, v1.y, v1.z, v1.w};
                short8 ah, al;
                #pragma unroll
                for (int i = 0; i < 8; ++i) {
                    unsigned int h = bf16rne(f[i]);
                    ah[i] = (short)h;
                    al[i] = (short)bf16rne(f[i] - __uint_as_float(h << 16));
                }
                #pragma unroll
                for (int nt = 0; nt < 2; ++nt) {
                    int nl = nt * 16 + m;
                    int cc = (kc * 4 + q) ^ m;
                    short8 bh = SH[nl * 16 + cc];
                    short8 bl = SL[nl * 16 + cc];
                    acc[nt] = __builtin_amdgcn_mfma_f32_16x16x32_bf16(ah, bh, acc[nt], 0, 0, 0);
                    acc[nt] = __builtin_amdgcn_mfma_f32_16x16x32_bf16(al, bh, acc[nt], 0, 0, 0);
                    acc[nt] = __builtin_amdgcn_mfma_f32_16x16x32_bf16(ah, bl, acc[nt], 0, 0, 0);
                }
            }
            #pragma unroll
            for (int nt = 0; nt < 2; ++nt) {
                int col = col0 + nt * 16 + m;
                float bias = (col >= DIM) ? b1[col - DIM] : 0.f;
                #pragma unroll
                for (int reg = 0; reg < 4; ++reg) {
                    int orow = row0 + q * 4 + reg;
                    if (orow < N_NODES) {
                        float v = acc[nt][reg];
                        if (col < DIM)
                            yb[orow * DIM + col] = (unsigned short)bf16rne(v);
                        else
                            r[orow * DIM + (col - DIM)] = v + bias;
                    }
                }
            }
        }
        __syncthreads();
    }
    grid.sync();

    // ---------------- P2: bucketsort ----------------
    for (int job = B; job < NBUCK; job += G) {
        const int s0 = boff[job], s1 = boff[job + 1];
        if (t < 64) sm.s.nh[t] = 0;
        __syncthreads();
        for (int i = s0 + t; i < s1; i += 256)
            atomicAdd(&sm.s.nh[((unsigned)part[i].x >> 16) & 63], 1);
        __syncthreads();
        if (t < 64) {
            int v = sm.s.nh[t];
            int xv = v;
            for (int s = 1; s < 64; s <<= 1) {
                int u = __shfl_up(xv, s);
                if (t >= s) xv += u;
            }
            int excl = xv - v;
            sm.s.ncur[t] = excl;
            int node = job * 64 + t;
            if (node < N_NODES) off[node] = s0 + excl;
        }
        __syncthreads();
        for (int i = s0 + t; i < s1; i += 256) {
            int2 rc = part[i];
            int dl = ((unsigned)rc.x >> 16) & 63;
            int p = atomicAdd(&sm.s.ncur[dl], 1);
            sorted[s0 + p] = make_int2(rc.x & 0xFFFF, rc.y);
        }
        if (job == 0 && t == 0) off[N_NODES] = N_EDGES;
        __syncthreads();
    }
    grid.sync();

    // ---------------- P3: agg (wave per node, 8 gathers in flight) ----------
    {
        const int lane = t & 63;
        const float2* r2 = (const float2*)r;
        const unsigned int* yb32 = (const unsigned int*)yb;
        float2 vr = ((const float2*)vrel)[lane];
        float2 vo = ((const float2*)vroot)[lane];
        for (int node = B * 4 + (t >> 6); node < N_NODES; node += G * 4) {
            int j = off[node];
            const int e1 = off[node + 1];
            float sx = 0.f, sy = 0.f;
            for (; j + 8 <= e1; j += 8) {
                int2 rc[8];
                #pragma unroll
                for (int u = 0; u < 8; ++u) rc[u] = sorted[j + u];
                unsigned int v[8];
                #pragma unroll
                for (int u = 0; u < 8; ++u) v[u] = yb32[rc[u].x * 64 + lane];
                #pragma unroll
                for (int u = 0; u < 8; ++u) {
                    float w = __int_as_float(rc[u].y);
                    sx = fmaf(w, __uint_as_float(v[u] << 16), sx);
                    sy = fmaf(w, __uint_as_float(v[u] & 0xFFFF0000u), sy);
                }
            }
            for (; j < e1; ++j) {
                int2 rcs = sorted[j];
                float w = __int_as_float(rcs.y);
                unsigned int vv = yb32[rcs.x * 64 + lane];
                sx = fmaf(w, __uint_as_float(vv << 16), sx);
                sy = fmaf(w, __uint_as_float(vv & 0xFFFF0000u), sy);
            }
            float2 rr = r2[(size_t)node * 64 + lane];
            float hx = fmaxf(sx + rr.x, 0.f);
            float hy = fmaxf(sy + rr.y, 0.f);
            float pa = hx * vr.x + hy * vr.y;
            float pb = hx * vo.x + hy * vo.y;
            for (int mm = 32; mm > 0; mm >>= 1) {
                pa += __shfl_xor(pa, mm);
                pb += __shfl_xor(pb, mm);
            }
            if (lane == 0) {
                aArr[node] = pa;
                bArr[node] = pb;
            }
        }
    }
    grid.sync();

    // ---------------- P4: reduce + final ----------------
    for (int i = t; i < NGRAPH; i += 256) { sm.rd.sbin[i] = 0.f; sm.rd.cbin[i] = 0; }
    __syncthreads();
    for (int i = B * 256 + t; i < N_EDGES; i += G * 256) {
        int2 rc = part[i];
        int srcn = rc.x & 0xFFFF;
        int dstn = (int)((unsigned)rc.x >> 16);
        atomicAdd(&sm.rd.sbin[batch[dstn]], __int_as_float(rc.y) * aArr[srcn]);
    }
    for (int n = B * 256 + t; n < N_NODES; n += G * 256) {
        int g = batch[n];
        atomicAdd(&sm.rd.sbin[g], bArr[n]);
        atomicAdd(&sm.rd.cbin[g], 1);
    }
    __syncthreads();
    if (t < NGRAPH) {
        if (sm.rd.sbin[t] != 0.f) atomicAdd(&gsum[t], sm.rd.sbin[t]);
        if (sm.rd.cbin[t]) atomicAdd(&gcntg[t], sm.rd.cbin[t]);
    }
    __syncthreads();
    if (t == 0) {
        __threadfence();
        flag = (atomicAdd(ticket_red, 1) == G - 1);
    }
    __syncthreads();
    if (flag && t < NGRAPH) {
        __threadfence();
        float S = __hip_atomic_load(&gsum[t], __ATOMIC_RELAXED, __HIP_MEMORY_SCOPE_AGENT);
        int C = __hip_atomic_load(&gcntg[t], __ATOMIC_RELAXED, __HIP_MEMORY_SCOPE_AGENT);
        float denom = (C > 0) ? (float)C : 1.f;
        float v = (S + (float)C * cb3[0]) / denom + blin[0];
        out[t] = (v > 0.f) ? v : 0.f;
    }
}

// ===========================================================================
// Fallback path: r9 six-kernel pipeline (known-good, 194 µs)
// ===========================================================================
__global__ __launch_bounds__(256) void k_front9(
    const int* __restrict__ dst,
    const float* __restrict__ Wrel, const float* __restrict__ Wroot,
    const float* __restrict__ W3rel, const float* __restrict__ W3root,
    const float* __restrict__ b3, const float* __restrict__ Wlin,
    unsigned short* __restrict__ wbh, unsigned short* __restrict__ wbl,
    int* __restrict__ ghist, int* __restrict__ ticket_hist,
    int* __restrict__ boff, int* __restrict__ gcursor,
    float* __restrict__ vrel, float* __restrict__ vroot, float* __restrict__ cb3) {
    const int t = threadIdx.x;
    const int blk = blockIdx.x;
    if (blk < NB_HIST) {
        __shared__ int lhist[NBUCK];
        __shared__ int islast;
        for (int i = t; i < NBUCK; i += 256) lhist[i] = 0;
        __syncthreads();
        const int e0 = blk * EPB;
        for (int i = 0; i < 8; ++i) {
            int e = e0 + i * 256 + t;
            if (e < N_EDGES) atomicAdd(&lhist[dst[e] >> 6], 1);
        }
        __syncthreads();
        for (int i = t; i < NBUCK; i += 256)
            if (lhist[i]) atomicAdd(&ghist[i], lhist[i]);
        __syncthreads();
        if (t == 0) {
            __threadfence();
            islast = (atomicAdd(ticket_hist, 1) == NB_HIST - 1);
        }
        __syncthreads();
        if (islast) {
            __threadfence();
            if (t < 64) {
                int carry = 0;
                for (int c = 0; c < 5; ++c) {
                    int idx = c * 64 + t;
                    int v = (idx < NBUCK)
                        ? __hip_atomic_load(&ghist[idx], __ATOMIC_RELAXED,
                                            __HIP_MEMORY_SCOPE_AGENT)
                        : 0;
                    int xv = v;
                    for (int s = 1; s < 64; s <<= 1) {
                        int u = __shfl_up(xv, s);
                        if (t >= s) xv += u;
                    }
                    int excl = carry + xv - v;
                    if (idx < NBUCK) { boff[idx] = excl; gcursor[idx] = excl; }
                    carry += __shfl(xv, 63);
                }
                if (t == 0) boff[NBUCK] = carry;
            }
        }
    } else if (blk < NB_HIST + NB_WCONV) {
        const int b = blk - NB_HIST;
        for (int i = b * 256 + t; i < 256 * DIM; i += NB_WCONV * 256) {
            int n = i >> 7, k = i & 127;
            float v = (n < DIM) ? Wrel[n * DIM + k] : Wroot[(n - DIM) * DIM + k];
            unsigned int h = bf16rne(v);
            wbh[i] = (unsigned short)h;
            wbl[i] = (unsigned short)bf16rne(v - __uint_as_float(h << 16));
        }
    } else {
        if (t < 64) {
            for (int kk = 0; kk < 2; ++kk) {
                int k = t + kk * 64;
                float sr = 0.f, so = 0.f;
                for (int h = 0; h < DIM; ++h) {
                    float wl = Wlin[h];
                    sr = fmaf(wl, W3rel[h * DIM + k], sr);
                    so = fmaf(wl, W3root[h * DIM + k], so);
                }
                vrel[k] = sr;
                vroot[k] = so;
            }
            float c = b3[t] * Wlin[t] + b3[t + 64] * Wlin[t + 64];
            for (int m = 32; m > 0; m >>= 1) c += __shfl_xor(c, m);
            if (t == 0) cb3[0] = c;
        }
    }
}

__global__ __launch_bounds__(256) void k_partition9(const int* __restrict__ src,
                                                    const int* __restrict__ dst,
                                                    const float* __restrict__ ew,
                                                    int* __restrict__ gcursor,
                                                    int2* __restrict__ part) {
    __shared__ int lhist[NBUCK], lbase[NBUCK], gbase[NBUCK], lcur[NBUCK];
    __shared__ int2 lrec[EPB];
    const int t = threadIdx.x;
    for (int i = t; i < NBUCK; i += 256) lhist[i] = 0;
    __syncthreads();
    const int e0 = blockIdx.x * EPB;
    const int tot = min(EPB, N_EDGES - e0);
    int mys[8], myd[8];
    float myw[8];
    for (int i = 0; i < 8; ++i) {
        int e = e0 + i * 256 + t;
        if (e < N_EDGES) {
            mys[i] = src[e];
            myd[i] = dst[e];
            myw[i] = ew[e];
            atomicAdd(&lhist[myd[i] >> 6], 1);
        } else {
            myd[i] = -1;
        }
    }
    __syncthreads();
    if (t < 64) {
        int carry = 0;
        for (int c = 0; c < 5; ++c) {
            int idx = c * 64 + t;
            int v = (idx < NBUCK) ? lhist[idx] : 0;
            int xv = v;
            for (int s = 1; s < 64; s <<= 1) {
                int u = __shfl_up(xv, s);
                if (t >= s) xv += u;
            }
            if (idx < NBUCK) { lbase[idx] = carry + xv - v; lcur[idx] = 0; }
            carry += __shfl(xv, 63);
        }
    }
    __syncthreads();
    for (int i = t; i < NBUCK; i += 256) {
        int cnt = lhist[i];
        gbase[i] = cnt ? atomicAdd(&gcursor[i], cnt) : 0;
    }
    __syncthreads();
    for (int i = 0; i < 8; ++i) {
        if (myd[i] >= 0) {
            int bb = myd[i] >> 6;
            int slot = lbase[bb] + atomicAdd(&lcur[bb], 1);
            lrec[slot] = make_int2((myd[i] << 16) | mys[i], __float_as_int(myw[i]));
        }
    }
    __syncthreads();
    for (int i = t; i < tot; i += 256) {
        int2 rc = lrec[i];
        int bb = ((unsigned)rc.x >> 16) >> 6;
        part[gbase[bb] + (i - lbase[bb])] = rc;
    }
}

__global__ __launch_bounds__(256) void k_gemm9(
    const float* __restrict__ x,
    const unsigned short* __restrict__ wbh, const unsigned short* __restrict__ wbl,
    const float* __restrict__ b1,
    unsigned short* __restrict__ yb, float* __restrict__ r) {
    extern __shared__ unsigned short smem[];
    uint4* sh = (uint4*)smem;
    uint4* sl = (uint4*)(smem + 16384);
    const int t = threadIdx.x;
    const int g = blockIdx.x;
    const int half = blockIdx.y;
    const int n0 = half * 128;
    const uint4* gh = (const uint4*)wbh + (size_t)n0 * 16;
    const uint4* gl = (const uint4*)wbl + (size_t)n0 * 16;
    for (int i = t; i < 2048; i += 256) {
        int row = i >> 4, c = i & 15;
        int sc = row * 16 + (c ^ (row & 15));
        sh[sc] = gh[i];
        sl[sc] = gl[i];
    }
    __syncthreads();
    const int lane = t & 63;
    const int m = lane & 15;
    const int q = lane >> 4;
    const int row0 = g * 64 + (t >> 6) * 16;
    const int row = row0 + m;
    const bool ok = row < N_NODES;
    const short8* SH = (const short8*)smem;
    const short8* SL = (const short8*)(smem + 16384);
    floatx4 acc[8];
    #pragma unroll
    for (int i = 0; i < 8; ++i) acc[i] = (floatx4)(0.f);
    #pragma unroll
    for (int kc = 0; kc < 4; ++kc) {
        float4 v0 = make_float4(0.f, 0.f, 0.f, 0.f);
        float4 v1 = make_float4(0.f, 0.f, 0.f, 0.f);
        if (ok) {
            const float4* xp = (const float4*)(x + (size_t)row * DIM + kc * 32 + q * 8);
            v0 = xp[0];
            v1 = xp[1];
        }
        float f[8] = {v0.x, v0.y, v0.z, v0.w, v1.x, v1.y, v1.z, v1.w};
        short8 ah, al;
        #pragma unroll
        for (int i = 0; i < 8; ++i) {
            unsigned int h = bf16rne(f[i]);
            ah[i] = (short)h;
            al[i] = (short)bf16rne(f[i] - __uint_as_float(h << 16));
        }
        #pragma unroll
        for (int nt = 0; nt < 8; ++nt) {
            int n = nt * 16 + m;
            int cc = (kc * 4 + q) ^ m;
            short8 bh = SH[n * 16 + cc];
            short8 bl = SL[n * 16 + cc];
            acc[nt] = __builtin_amdgcn_mfma_f32_16x16x32_bf16(ah, bh, acc[nt], 0, 0, 0);
            acc[nt] = __builtin_amdgcn_mfma_f32_16x16x32_bf16(al, bh, acc[nt], 0, 0, 0);
            acc[nt] = __builtin_amdgcn_mfma_f32_16x16x32_bf16(ah, bl, acc[nt], 0, 0, 0);
        }
    }
    #pragma unroll
    for (int nt = 0; nt < 8; ++nt) {
        int col = n0 + nt * 16 + m;
        float bias = (col >= DIM) ? b1[col - DIM] : 0.f;
        #pragma unroll
        for (int reg = 0; reg < 4; ++reg) {
            int orow = row0 + q * 4 + reg;
            if (orow < N_NODES) {
                float v = acc[nt][reg];
                if (col < DIM)
                    yb[orow * DIM + col] = (unsigned short)bf16rne(v);
                else
                    r[orow * DIM + (col - DIM)] = v + bias;
            }
        }
    }
}

__global__ __launch_bounds__(256) void k_bucketsort9(const int* __restrict__ boff,
                                                     const int2* __restrict__ part,
                                                     int2* __restrict__ sorted,
                                                     int* __restrict__ off) {
    __shared__ int nh[64], ncur[64];
    const int b = blockIdx.x;
    const int t = threadIdx.x;
    const int s0 = boff[b], s1 = boff[b + 1];
    if (t < 64) nh[t] = 0;
    __syncthreads();
    for (int i = s0 + t; i < s1; i += 256)
        atomicAdd(&nh[((unsigned)part[i].x >> 16) & 63], 1);
    __syncthreads();
    if (t < 64) {
        int v = nh[t];
        int xv = v;
        for (int s = 1; s < 64; s <<= 1) {
            int u = __shfl_up(xv, s);
            if (t >= s) xv += u;
        }
        int excl = xv - v;
        ncur[t] = excl;
        int node = b * 64 + t;
        if (node < N_NODES) off[node] = s0 + excl;
    }
    __syncthreads();
    for (int i = s0 + t; i < s1; i += 256) {
        int2 rc = part[i];
        int dl = ((unsigned)rc.x >> 16) & 63;
        int p = atomicAdd(&ncur[dl], 1);
        sorted[s0 + p] = make_int2(rc.x & 0xFFFF, rc.y);
    }
    if (b == 0 && t == 0) off[N_NODES] = N_EDGES;
}

__global__ __launch_bounds__(256) void k_agg9(const unsigned int* __restrict__ yb,
                                              const float2* __restrict__ r2,
                                              const int* __restrict__ off,
                                              const int2* __restrict__ grec,
                                              const float2* __restrict__ vrel2,
                                              const float2* __restrict__ vroot2,
                                              float* __restrict__ aout,
                                              float* __restrict__ bout) {
    const int lane = threadIdx.x & 63;
    const int node = blockIdx.x * 4 + (threadIdx.x >> 6);
    if (node >= N_NODES) return;
    int j = off[node];
    const int e1 = off[node + 1];
    float sx = 0.f, sy = 0.f;
    for (; j + 4 <= e1; j += 4) {
        int2 r0 = grec[j], r1 = grec[j + 1], rr2 = grec[j + 2], r3 = grec[j + 3];
        float w0 = __int_as_float(r0.y), w1 = __int_as_float(r1.y);
        float w2 = __int_as_float(rr2.y), w3 = __int_as_float(r3.y);
        unsigned int v0 = yb[r0.x * 64 + lane];
        unsigned int v1 = yb[r1.x * 64 + lane];
        unsigned int v2 = yb[rr2.x * 64 + lane];
        unsigned int v3 = yb[r3.x * 64 + lane];
        sx = fmaf(w0, __uint_as_float(v0 << 16),
             fmaf(w1, __uint_as_float(v1 << 16),
             fmaf(w2, __uint_as_float(v2 << 16),
             fmaf(w3, __uint_as_float(v3 << 16), sx))));
        sy = fmaf(w0, __uint_as_float(v0 & 0xFFFF0000u),
             fmaf(w1, __uint_as_float(v1 & 0xFFFF0000u),
             fmaf(w2, __uint_as_float(v2 & 0xFFFF0000u),
             fmaf(w3, __uint_as_float(v3 & 0xFFFF0000u), sy))));
    }
    for (; j < e1; ++j) {
        int2 rc = grec[j];
        float w = __int_as_float(rc.y);
        unsigned int v = yb[rc.x * 64 + lane];
        sx = fmaf(w, __uint_as_float(v << 16), sx);
        sy = fmaf(w, __uint_as_float(v & 0xFFFF0000u), sy);
    }
    float2 rr = r2[(size_t)node * 64 + lane];
    float hx = fmaxf(sx + rr.x, 0.f);
    float hy = fmaxf(sy + rr.y, 0.f);
    float2 vr = vrel2[lane];
    float2 vo = vroot2[lane];
    float pa = hx * vr.x + hy * vr.y;
    float pb = hx * vo.x + hy * vo.y;
    for (int mm = 32; mm > 0; mm >>= 1) {
        pa += __shfl_xor(pa, mm);
        pb += __shfl_xor(pb, mm);
    }
    if (lane == 0) {
        aout[node] = pa;
        bout[node] = pb;
    }
}

__global__ __launch_bounds__(256) void k_reduce_final9(
    const int2* __restrict__ sorted, const int* __restrict__ off,
    const float* __restrict__ a, const float* __restrict__ bvec,
    const int* __restrict__ batch,
    float* __restrict__ gpart, int* __restrict__ gpartc,
    int* __restrict__ ticket_red,
    const float* __restrict__ cb3, const float* __restrict__ blin,
    float* __restrict__ out) {
    __shared__ float sbin[NGRAPH];
    __shared__ int cbin[NGRAPH];
    __shared__ int islast;
    const int t = threadIdx.x;
    for (int i = t; i < NGRAPH; i += 256) { sbin[i] = 0.f; cbin[i] = 0; }
    __syncthreads();
    const int lane = t & 63;
    const int gw = blockIdx.x * 4 + (t >> 6);
    const int nw = gridDim.x * 4;
    for (int node = gw; node < N_NODES; node += nw) {
        const int e0 = off[node], e1 = off[node + 1];
        float s = 0.f;
        for (int j = e0 + lane; j < e1; j += 64) {
            int2 rc = sorted[j];
            s = fmaf(__int_as_float(rc.y), a[rc.x], s);
        }
        for (int mm = 32; mm > 0; mm >>= 1) s += __shfl_xor(s, mm);
        if (lane == 0) {
            int g = batch[node];
            atomicAdd(&sbin[g], s + bvec[node]);
            atomicAdd(&cbin[g], 1);
        }
    }
    __syncthreads();
    const int slot = blockIdx.x & 63;
    for (int i = t; i < NGRAPH; i += 256) {
        atomicAdd(&gpart[slot * NGRAPH + i], sbin[i]);
        if (cbin[i]) atomicAdd(&gpartc[slot * NGRAPH + i], cbin[i]);
    }
    __syncthreads();
    if (t == 0) {
        __threadfence();
        islast = (atomicAdd(ticket_red, 1) == (int)gridDim.x - 1);
    }
    __syncthreads();
    if (islast) {
        __threadfence();
        if (t < NGRAPH) {
            float S = 0.f;
            int C = 0;
            for (int s2 = 0; s2 < 64; ++s2) {
                S += __hip_atomic_load(&gpart[s2 * NGRAPH + t], __ATOMIC_RELAXED,
                                       __HIP_MEMORY_SCOPE_AGENT);
                C += __hip_atomic_load(&gpartc[s2 * NGRAPH + t], __ATOMIC_RELAXED,
                                       __HIP_MEMORY_SCOPE_AGENT);
            }
            float denom = (C > 0) ? (float)C : 1.f;
            float v = (S + (float)C * cb3[0]) / denom + blin[0];
            out[t] = (v > 0.f) ? v : 0.f;
        }
    }
}

// ---------------------------------------------------------------------------
extern "C" void kernel_launch(void* const* d_in, const int* in_sizes, int n_in,
                              void* d_out, int out_size, void* d_ws, size_t ws_size,
                              hipStream_t stream) {
    const float* x = (const float*)d_in[0];
    const int* edge_index = (const int*)d_in[1];
    const int* src = edge_index;
    const int* dst = edge_index + N_EDGES;
    const int* batch = (const int*)d_in[2];
    const float* ew = (const float*)d_in[3];
    const float* W1rel = (const float*)d_in[4];
    const float* b1 = (const float*)d_in[5];
    const float* W1root = (const float*)d_in[6];
    const float* W3rel = (const float*)d_in[7];
    const float* b3 = (const float*)d_in[8];
    const float* W3root = (const float*)d_in[9];
    const float* Wlin = (const float*)d_in[10];
    const float* blin = (const float*)d_in[11];
    float* out = (float*)d_out;

    char* w = (char*)d_ws;
    size_t o = 0;
    auto alloc = [&](size_t bytes) -> void* {
        void* p = w + o;
        o += bytes;
        o = (o + 255) & ~(size_t)255;
        return p;
    };
    int* zr = (int*)alloc(NZERO * 4);                       // mega comm
    char* zbase9 = (char*)alloc(1280 + 64 * NGRAPH * 4 * 2);  // fallback comm
    int* ghist9 = (int*)zbase9;
    int* ticket_hist9 = ghist9 + NBUCK;
    int* ticket_red9 = ghist9 + NBUCK + 1;
    float* gpart9 = (float*)(zbase9 + 1280);
    int* gpartc9 = (int*)(zbase9 + 1280 + 64 * NGRAPH * 4);
    const size_t zbytes9 = 1280 + 64 * NGRAPH * 4 * 2;

    unsigned short* wbh = (unsigned short*)alloc((size_t)256 * DIM * 2);
    unsigned short* wbl = (unsigned short*)alloc((size_t)256 * DIM * 2);
    unsigned short* yb = (unsigned short*)alloc((size_t)N_NODES * DIM * 2);
    float* r = (float*)alloc((size_t)N_NODES * DIM * 4);
    int* boff = (int*)alloc((size_t)(NBUCK + 1) * 4);
    int* gcursor = (int*)alloc((size_t)NBUCK * 4);
    int2* part = (int2*)alloc((size_t)N_EDGES * 8);
    int2* sorted = (int2*)alloc((size_t)N_EDGES * 8);
    int* off = (int*)alloc((size_t)(N_NODES + 1) * 4);
    float* a = (float*)alloc((size_t)N_NODES * 4);
    float* b = (float*)alloc((size_t)N_NODES * 4);
    float* vrel = (float*)alloc(DIM * 4);
    float* vroot = (float*)alloc(DIM * 4);
    float* cb3 = (float*)alloc(4);

    void* args[] = {
        (void*)&src, (void*)&dst, (void*)&ew, (void*)&batch, (void*)&x,
        (void*)&W1rel, (void*)&b1, (void*)&W1root,
        (void*)&W3rel, (void*)&b3, (void*)&W3root,
        (void*)&Wlin, (void*)&blin,
        (void*)&wbh, (void*)&wbl, (void*)&yb, (void*)&r,
        (void*)&zr, (void*)&boff, (void*)&gcursor,
        (void*)&part, (void*)&sorted, (void*)&off,
        (void*)&a, (void*)&b, (void*)&vrel, (void*)&vroot, (void*)&cb3,
        (void*)&out};

    hipError_t cerr = hipLaunchCooperativeKernel(
        (const void*)mega, dim3(GRID), dim3(256), (void**)args, 0, stream);

    if (cerr != hipSuccess) {
        (void)hipGetLastError();  // clear sticky error, take fallback path
        hipMemsetAsync(zbase9, 0, zbytes9, stream);
        k_front9<<<NB_HIST + NB_WCONV + 1, 256, 0, stream>>>(
            dst, W1rel, W1root, W3rel, W3root, b3, Wlin,
            wbh, wbl, ghist9, ticket_hist9, boff, gcursor, vrel, vroot, cb3);
        k_partition9<<<NB_HIST, 256, 0, stream>>>(src, dst, ew, gcursor, part);
        k_gemm9<<<dim3(NBUCK, 2), 256, 65536, stream>>>(x, wbh, wbl, b1, yb, r);
        k_bucketsort9<<<NBUCK, 256, 0, stream>>>(boff, part, sorted, off);
        k_agg9<<<(N_NODES + 3) / 4, 256, 0, stream>>>(
            (const unsigned int*)yb, (const float2*)r, off, sorted,
            (const float2*)vrel, (const float2*)vroot, a, b);
        k_reduce_final9<<<RED_BLOCKS, 256, 0, stream>>>(
            sorted, off, a, b, batch, gpart9, gpartc9, ticket_red9, cb3, blin, out);
    }
}

// Round 12
// 200.141 us; speedup vs baseline: 3.6722x; 3.6722x over previous
//
#include <hip/hip_runtime.h>

#define N_NODES 20000
#define N_EDGES 640000
#define DIM 128
#define NGRAPH 64
#define NBUCK 313          // ceil(20000/64) dst buckets of 64 nodes
#define EPB 1024           // edges per histogram/partition chunk (was 2048)
#define NB_EDGEJ 625       // ceil(640000/1024)
#define NB_WCONV 32
#define RED_BLOCKS 512

typedef __attribute__((ext_vector_type(8))) short short8;
typedef __attribute__((ext_vector_type(4))) float floatx4;

__device__ __forceinline__ unsigned int bf16rne(float f) {
    unsigned int u = __float_as_uint(f);
    return (u + 0x7FFFu + ((u >> 16) & 1u)) >> 16;
}

// ---------------------------------------------------------------------------
// K_front: [dst-bucket histogram (625 jobs) + last-block scan | weight
// split-bf16 convert | params]
// ---------------------------------------------------------------------------
__global__ __launch_bounds__(256) void k_front(
    const int* __restrict__ dst,
    const float* __restrict__ Wrel, const float* __restrict__ Wroot,
    const float* __restrict__ W3rel, const float* __restrict__ W3root,
    const float* __restrict__ b3, const float* __restrict__ Wlin,
    unsigned short* __restrict__ wbh, unsigned short* __restrict__ wbl,
    int* __restrict__ ghist, int* __restrict__ ticket_hist,
    int* __restrict__ boff, int* __restrict__ gcursor,
    float* __restrict__ vrel, float* __restrict__ vroot, float* __restrict__ cb3) {

    const int t = threadIdx.x;
    const int blk = blockIdx.x;

    if (blk < NB_EDGEJ) {
        __shared__ int lhist[NBUCK];
        __shared__ int islast;
        for (int i = t; i < NBUCK; i += 256) lhist[i] = 0;
        __syncthreads();
        const int e0 = blk * EPB;
        for (int i = 0; i < 4; ++i) {
            int e = e0 + i * 256 + t;
            if (e < N_EDGES) atomicAdd(&lhist[dst[e] >> 6], 1);
        }
        __syncthreads();
        for (int i = t; i < NBUCK; i += 256)
            if (lhist[i]) atomicAdd(&ghist[i], lhist[i]);
        __syncthreads();
        if (t == 0) {
            __threadfence();
            islast = (atomicAdd(ticket_hist, 1) == NB_EDGEJ - 1);
        }
        __syncthreads();
        if (islast) {
            __threadfence();
            if (t < 64) {
                int carry = 0;
                for (int c = 0; c < 5; ++c) {
                    int idx = c * 64 + t;
                    int v = (idx < NBUCK)
                        ? __hip_atomic_load(&ghist[idx], __ATOMIC_RELAXED,
                                            __HIP_MEMORY_SCOPE_AGENT)
                        : 0;
                    int xv = v;
                    for (int s = 1; s < 64; s <<= 1) {
                        int u = __shfl_up(xv, s);
                        if (t >= s) xv += u;
                    }
                    int excl = carry + xv - v;
                    if (idx < NBUCK) { boff[idx] = excl; gcursor[idx] = excl; }
                    carry += __shfl(xv, 63);
                }
                if (t == 0) boff[NBUCK] = carry;
            }
        }
    } else if (blk < NB_EDGEJ + NB_WCONV) {
        const int b = blk - NB_EDGEJ;
        for (int i = b * 256 + t; i < 256 * DIM; i += NB_WCONV * 256) {
            int n = i >> 7, k = i & 127;
            float v = (n < DIM) ? Wrel[n * DIM + k] : Wroot[(n - DIM) * DIM + k];
            unsigned int h = bf16rne(v);
            wbh[i] = (unsigned short)h;
            wbl[i] = (unsigned short)bf16rne(v - __uint_as_float(h << 16));
        }
    } else {
        if (t < 64) {
            for (int kk = 0; kk < 2; ++kk) {
                int k = t + kk * 64;
                float sr = 0.f, so = 0.f;
                for (int h = 0; h < DIM; ++h) {
                    float wl = Wlin[h];
                    sr = fmaf(wl, W3rel[h * DIM + k], sr);
                    so = fmaf(wl, W3root[h * DIM + k], so);
                }
                vrel[k] = sr;
                vroot[k] = so;
            }
            float c = b3[t] * Wlin[t] + b3[t + 64] * Wlin[t + 64];
            for (int m = 32; m > 0; m >>= 1) c += __shfl_xor(c, m);
            if (t == 0) cb3[0] = c;
        }
    }
}

// ---------------------------------------------------------------------------
// K_partition: 625 blocks x 1024 edges; LDS reorder -> coalesced runs.
// record.x = (dst<<16)|src
// ---------------------------------------------------------------------------
__global__ __launch_bounds__(256) void k_partition(const int* __restrict__ src,
                                                   const int* __restrict__ dst,
                                                   const float* __restrict__ ew,
                                                   int* __restrict__ gcursor,
                                                   int2* __restrict__ part) {
    __shared__ int lhist[NBUCK], lbase[NBUCK], gbase[NBUCK], lcur[NBUCK];
    __shared__ int2 lrec[EPB];   // 8 KB
    const int t = threadIdx.x;
    for (int i = t; i < NBUCK; i += 256) lhist[i] = 0;
    __syncthreads();
    const int e0 = blockIdx.x * EPB;
    const int tot = min(EPB, N_EDGES - e0);
    int mys[4], myd[4];
    float myw[4];
    for (int i = 0; i < 4; ++i) {
        int e = e0 + i * 256 + t;
        if (e < N_EDGES) {
            mys[i] = src[e];
            myd[i] = dst[e];
            myw[i] = ew[e];
            atomicAdd(&lhist[myd[i] >> 6], 1);
        } else {
            myd[i] = -1;
        }
    }
    __syncthreads();
    if (t < 64) {
        int carry = 0;
        for (int c = 0; c < 5; ++c) {
            int idx = c * 64 + t;
            int v = (idx < NBUCK) ? lhist[idx] : 0;
            int xv = v;
            for (int s = 1; s < 64; s <<= 1) {
                int u = __shfl_up(xv, s);
                if (t >= s) xv += u;
            }
            if (idx < NBUCK) { lbase[idx] = carry + xv - v; lcur[idx] = 0; }
            carry += __shfl(xv, 63);
        }
    }
    __syncthreads();
    for (int i = t; i < NBUCK; i += 256) {
        int cnt = lhist[i];
        gbase[i] = cnt ? atomicAdd(&gcursor[i], cnt) : 0;
    }
    __syncthreads();
    for (int i = 0; i < 4; ++i) {
        if (myd[i] >= 0) {
            int bb = myd[i] >> 6;
            int slot = lbase[bb] + atomicAdd(&lcur[bb], 1);
            lrec[slot] = make_int2((myd[i] << 16) | mys[i], __float_as_int(myw[i]));
        }
    }
    __syncthreads();
    for (int i = t; i < tot; i += 256) {
        int2 rc = lrec[i];
        int bb = ((unsigned)rc.x >> 16) >> 6;
        part[gbase[bb] + (i - lbase[bb])] = rc;
    }
}

// ---------------------------------------------------------------------------
// K_gemm: split-bf16 MFMA GEMM; 64-row x 64-col quarter tiles, 32 KB LDS
// (4 blocks/CU). x hi/lo split in-register. D = Ah*Bh + Al*Bh + Ah*Bl.
// grid = (313, 4)
// ---------------------------------------------------------------------------
__global__ __launch_bounds__(256) void k_gemm(
    const float* __restrict__ x,
    const unsigned short* __restrict__ wbh, const unsigned short* __restrict__ wbl,
    const float* __restrict__ b1,
    unsigned short* __restrict__ yb, float* __restrict__ r) {
    extern __shared__ unsigned short smem[];   // [0,16KB) hi, [16KB,32KB) lo
    uint4* sh = (uint4*)smem;
    uint4* sl = (uint4*)(smem + 8192);

    const int t = threadIdx.x;
    const int g = blockIdx.x;
    const int col0 = blockIdx.y * 64;

    const uint4* gh = (const uint4*)wbh + (size_t)col0 * 16;
    const uint4* gl = (const uint4*)wbl + (size_t)col0 * 16;
    for (int i = t; i < 1024; i += 256) {
        int row = i >> 4, c = i & 15;
        int sc = row * 16 + (c ^ (row & 15));
        sh[sc] = gh[i];
        sl[sc] = gl[i];
    }
    __syncthreads();

    const int lane = t & 63;
    const int m = lane & 15;
    const int q = lane >> 4;
    const int row0 = g * 64 + (t >> 6) * 16;
    const int row = row0 + m;
    const bool ok = row < N_NODES;

    const short8* SH = (const short8*)smem;
    const short8* SL = (const short8*)(smem + 8192);

    floatx4 acc[4];
    #pragma unroll
    for (int i = 0; i < 4; ++i) acc[i] = (floatx4)(0.f);

    #pragma unroll
    for (int kc = 0; kc < 4; ++kc) {
        float4 v0 = make_float4(0.f, 0.f, 0.f, 0.f);
        float4 v1 = make_float4(0.f, 0.f, 0.f, 0.f);
        if (ok) {
            const float4* xp = (const float4*)(x + (size_t)row * DIM + kc * 32 + q * 8);
            v0 = xp[0];
            v1 = xp[1];
        }
        float f[8] = {v0.x, v0.y, v0.z, v0.w, v1.x, v1.y, v1.z, v1.w};
        short8 ah, al;
        #pragma unroll
        for (int i = 0; i < 8; ++i) {
            unsigned int h = bf16rne(f[i]);
            ah[i] = (short)h;
            al[i] = (short)bf16rne(f[i] - __uint_as_float(h << 16));
        }
        #pragma unroll
        for (int nt = 0; nt < 4; ++nt) {
            int nl = nt * 16 + m;
            int cc = (kc * 4 + q) ^ m;
            short8 bh = SH[nl * 16 + cc];
            short8 bl = SL[nl * 16 + cc];
            acc[nt] = __builtin_amdgcn_mfma_f32_16x16x32_bf16(ah, bh, acc[nt], 0, 0, 0);
            acc[nt] = __builtin_amdgcn_mfma_f32_16x16x32_bf16(al, bh, acc[nt], 0, 0, 0);
            acc[nt] = __builtin_amdgcn_mfma_f32_16x16x32_bf16(ah, bl, acc[nt], 0, 0, 0);
        }
    }

    // epilogue: C/D layout col=lane&15, row=q*4+reg
    #pragma unroll
    for (int nt = 0; nt < 4; ++nt) {
        int col = col0 + nt * 16 + m;
        float bias = (col >= DIM) ? b1[col - DIM] : 0.f;
        #pragma unroll
        for (int reg = 0; reg < 4; ++reg) {
            int orow = row0 + q * 4 + reg;
            if (orow < N_NODES) {
                float v = acc[nt][reg];
                if (col < DIM)
                    yb[orow * DIM + col] = (unsigned short)bf16rne(v);
                else
                    r[orow * DIM + (col - DIM)] = v + bias;
            }
        }
    }
}

// ---------------------------------------------------------------------------
// K_bucketsort: counting-sort each bucket by node; emit CSR off
// ---------------------------------------------------------------------------
__global__ __launch_bounds__(256) void k_bucketsort(const int* __restrict__ boff,
                                                    const int2* __restrict__ part,
                                                    int2* __restrict__ sorted,
                                                    int* __restrict__ off) {
    __shared__ int nh[64], ncur[64];
    const int b = blockIdx.x;
    const int t = threadIdx.x;
    const int s0 = boff[b], s1 = boff[b + 1];
    if (t < 64) nh[t] = 0;
    __syncthreads();
    for (int i = s0 + t; i < s1; i += 256)
        atomicAdd(&nh[((unsigned)part[i].x >> 16) & 63], 1);
    __syncthreads();
    if (t < 64) {
        int v = nh[t];
        int xv = v;
        for (int s = 1; s < 64; s <<= 1) {
            int u = __shfl_up(xv, s);
            if (t >= s) xv += u;
        }
        int excl = xv - v;
        ncur[t] = excl;
        int node = b * 64 + t;
        if (node < N_NODES) off[node] = s0 + excl;
    }
    __syncthreads();
    for (int i = s0 + t; i < s1; i += 256) {
        int2 rc = part[i];
        int dl = ((unsigned)rc.x >> 16) & 63;
        int p = atomicAdd(&ncur[dl], 1);
        sorted[s0 + p] = make_int2(rc.x & 0xFFFF, rc.y);
    }
    if (b == 0 && t == 0) off[N_NODES] = N_EDGES;
}

// ---------------------------------------------------------------------------
// K_agg: wave per node; 8 y-gathers in flight; h1=relu(agg+r); a,b dots
// ---------------------------------------------------------------------------
__global__ __launch_bounds__(256) void k_agg(const unsigned int* __restrict__ yb,
                                             const float2* __restrict__ r2,
                                             const int* __restrict__ off,
                                             const int2* __restrict__ grec,
                                             const float2* __restrict__ vrel2,
                                             const float2* __restrict__ vroot2,
                                             float* __restrict__ aout,
                                             float* __restrict__ bout) {
    const int lane = threadIdx.x & 63;
    const int node = blockIdx.x * 4 + (threadIdx.x >> 6);
    if (node >= N_NODES) return;

    int j = off[node];
    const int e1 = off[node + 1];
    float sx = 0.f, sy = 0.f;
    for (; j + 8 <= e1; j += 8) {
        int2 rc[8];
        #pragma unroll
        for (int u = 0; u < 8; ++u) rc[u] = grec[j + u];
        unsigned int v[8];
        #pragma unroll
        for (int u = 0; u < 8; ++u) v[u] = yb[rc[u].x * 64 + lane];
        #pragma unroll
        for (int u = 0; u < 8; ++u) {
            float w = __int_as_float(rc[u].y);
            sx = fmaf(w, __uint_as_float(v[u] << 16), sx);
            sy = fmaf(w, __uint_as_float(v[u] & 0xFFFF0000u), sy);
        }
    }
    for (; j < e1; ++j) {
        int2 rcs = grec[j];
        float w = __int_as_float(rcs.y);
        unsigned int vv = yb[rcs.x * 64 + lane];
        sx = fmaf(w, __uint_as_float(vv << 16), sx);
        sy = fmaf(w, __uint_as_float(vv & 0xFFFF0000u), sy);
    }
    float2 rr = r2[(size_t)node * 64 + lane];
    float hx = fmaxf(sx + rr.x, 0.f);
    float hy = fmaxf(sy + rr.y, 0.f);
    float2 vr = vrel2[lane];
    float2 vo = vroot2[lane];
    float pa = hx * vr.x + hy * vr.y;
    float pb = hx * vo.x + hy * vo.y;
    for (int mm = 32; mm > 0; mm >>= 1) {
        pa += __shfl_xor(pa, mm);
        pb += __shfl_xor(pb, mm);
    }
    if (lane == 0) {
        aout[node] = pa;
        bout[node] = pb;
    }
}

// ---------------------------------------------------------------------------
// K_reduce_final: wave per node; bin by graph; spread partials; last block -> out
// ---------------------------------------------------------------------------
__global__ __launch_bounds__(256) void k_reduce_final(
    const int2* __restrict__ sorted, const int* __restrict__ off,
    const float* __restrict__ a, const float* __restrict__ bvec,
    const int* __restrict__ batch,
    float* __restrict__ gpart, int* __restrict__ gpartc,
    int* __restrict__ ticket_red,
    const float* __restrict__ cb3, const float* __restrict__ blin,
    float* __restrict__ out) {
    __shared__ float sbin[NGRAPH];
    __shared__ int cbin[NGRAPH];
    __shared__ int islast;
    const int t = threadIdx.x;
    for (int i = t; i < NGRAPH; i += 256) { sbin[i] = 0.f; cbin[i] = 0; }
    __syncthreads();
    const int lane = t & 63;
    const int gw = blockIdx.x * 4 + (t >> 6);
    const int nw = gridDim.x * 4;
    for (int node = gw; node < N_NODES; node += nw) {
        const int e0 = off[node], e1 = off[node + 1];
        float s = 0.f;
        for (int j = e0 + lane; j < e1; j += 64) {
            int2 rc = sorted[j];
            s = fmaf(__int_as_float(rc.y), a[rc.x], s);
        }
        for (int mm = 32; mm > 0; mm >>= 1) s += __shfl_xor(s, mm);
        if (lane == 0) {
            int g = batch[node];
            atomicAdd(&sbin[g], s + bvec[node]);
            atomicAdd(&cbin[g], 1);
        }
    }
    __syncthreads();
    const int slot = blockIdx.x & 63;
    for (int i = t; i < NGRAPH; i += 256) {
        atomicAdd(&gpart[slot * NGRAPH + i], sbin[i]);
        if (cbin[i]) atomicAdd(&gpartc[slot * NGRAPH + i], cbin[i]);
    }
    __syncthreads();
    if (t == 0) {
        __threadfence();
        islast = (atomicAdd(ticket_red, 1) == (int)gridDim.x - 1);
    }
    __syncthreads();
    if (islast) {
        __threadfence();
        if (t < NGRAPH) {
            float S = 0.f;
            int C = 0;
            for (int s2 = 0; s2 < 64; ++s2) {
                S += __hip_atomic_load(&gpart[s2 * NGRAPH + t], __ATOMIC_RELAXED,
                                       __HIP_MEMORY_SCOPE_AGENT);
                C += __hip_atomic_load(&gpartc[s2 * NGRAPH + t], __ATOMIC_RELAXED,
                                       __HIP_MEMORY_SCOPE_AGENT);
            }
            float denom = (C > 0) ? (float)C : 1.f;
            float v = (S + (float)C * cb3[0]) / denom + blin[0];
            out[t] = (v > 0.f) ? v : 0.f;
        }
    }
}

// ---------------------------------------------------------------------------
extern "C" void kernel_launch(void* const* d_in, const int* in_sizes, int n_in,
                              void* d_out, int out_size, void* d_ws, size_t ws_size,
                              hipStream_t stream) {
    const float* x = (const float*)d_in[0];
    const int* edge_index = (const int*)d_in[1];
    const int* src = edge_index;
    const int* dst = edge_index + N_EDGES;
    const int* batch = (const int*)d_in[2];
    const float* ew = (const float*)d_in[3];
    const float* W1rel = (const float*)d_in[4];
    const float* b1 = (const float*)d_in[5];
    const float* W1root = (const float*)d_in[6];
    const float* W3rel = (const float*)d_in[7];
    const float* b3 = (const float*)d_in[8];
    const float* W3root = (const float*)d_in[9];
    const float* Wlin = (const float*)d_in[10];
    const float* blin = (const float*)d_in[11];
    float* out = (float*)d_out;

    char* w = (char*)d_ws;
    size_t o = 0;
    auto alloc = [&](size_t bytes) -> void* {
        void* p = w + o;
        o += bytes;
        o = (o + 255) & ~(size_t)255;
        return p;
    };
    char* zbase = (char*)alloc(1280 + 64 * NGRAPH * 4 * 2);
    int* ghist = (int*)zbase;
    int* ticket_hist = ghist + NBUCK;
    int* ticket_red = ghist + NBUCK + 1;
    float* gpart = (float*)(zbase + 1280);
    int* gpartc = (int*)(zbase + 1280 + 64 * NGRAPH * 4);
    const size_t zbytes = 1280 + 64 * NGRAPH * 4 * 2;

    unsigned short* wbh = (unsigned short*)alloc((size_t)256 * DIM * 2);
    unsigned short* wbl = (unsigned short*)alloc((size_t)256 * DIM * 2);
    unsigned short* yb = (unsigned short*)alloc((size_t)N_NODES * DIM * 2);
    float* r = (float*)alloc((size_t)N_NODES * DIM * 4);
    int* boff = (int*)alloc((size_t)(NBUCK + 1) * 4);
    int* gcursor = (int*)alloc((size_t)NBUCK * 4);
    int2* part = (int2*)alloc((size_t)N_EDGES * 8);
    int2* sorted = (int2*)alloc((size_t)N_EDGES * 8);
    int* off = (int*)alloc((size_t)(N_NODES + 1) * 4);
    float* a = (float*)alloc((size_t)N_NODES * 4);
    float* b = (float*)alloc((size_t)N_NODES * 4);
    float* vrel = (float*)alloc(DIM * 4);
    float* vroot = (float*)alloc(DIM * 4);
    float* cb3 = (float*)alloc(4);

    hipMemsetAsync(zbase, 0, zbytes, stream);

    k_front<<<NB_EDGEJ + NB_WCONV + 1, 256, 0, stream>>>(
        dst, W1rel, W1root, W3rel, W3root, b3, Wlin,
        wbh, wbl, ghist, ticket_hist, boff, gcursor, vrel, vroot, cb3);

    k_partition<<<NB_EDGEJ, 256, 0, stream>>>(src, dst, ew, gcursor, part);

    k_gemm<<<dim3(NBUCK, 4), 256, 32768, stream>>>(x, wbh, wbl, b1, yb, r);

    k_bucketsort<<<NBUCK, 256, 0, stream>>>(boff, part, sorted, off);

    k_agg<<<(N_NODES + 3) / 4, 256, 0, stream>>>(
        (const unsigned int*)yb, (const float2*)r, off, sorted,
        (const float2*)vrel, (const float2*)vroot, a, b);

    k_reduce_final<<<RED_BLOCKS, 256, 0, stream>>>(
        sorted, off, a, b, batch, gpart, gpartc, ticket_red, cb3, blin, out);
}

// Round 13
// 181.552 us; speedup vs baseline: 4.0482x; 1.1024x over previous
//
#include <hip/hip_runtime.h>

#define N_NODES 20000
#define N_EDGES 640000
#define DIM 128
#define NGRAPH 64
#define NBUCK 313          // ceil(20000/64) dst buckets of 64 nodes
#define CAP 2560           // padded records per bucket (mean 2048, 11 sigma)
#define EPB 1024           // edges per partition chunk
#define NB_PART 625        // ceil(640000/1024)
#define NB_WCONV 32
#define NB_GEMM 1252       // 313 row-tiles x 4 col-tiles
#define RED_BLOCKS 512

typedef __attribute__((ext_vector_type(8))) short short8;
typedef __attribute__((ext_vector_type(4))) float floatx4;

__device__ __forceinline__ unsigned int bf16rne(float f) {
    unsigned int u = __float_as_uint(f);
    return (u + 0x7FFFu + ((u >> 16) & 1u)) >> 16;
}

// ---------------------------------------------------------------------------
// K1: fused [edge partition into fixed-capacity buckets | weight split-bf16
// convert | params]. No histogram/scan pass: bucket b owns part[b*CAP ..).
// record.x = (dst<<16)|src
// ---------------------------------------------------------------------------
__global__ __launch_bounds__(256) void k_part_prep(
    const int* __restrict__ src, const int* __restrict__ dst,
    const float* __restrict__ ew,
    const float* __restrict__ W1rel, const float* __restrict__ W1root,
    const float* __restrict__ W3rel, const float* __restrict__ W3root,
    const float* __restrict__ b3, const float* __restrict__ Wlin,
    int* __restrict__ gcursor, int2* __restrict__ part,
    unsigned short* __restrict__ wbh, unsigned short* __restrict__ wbl,
    float* __restrict__ vrel, float* __restrict__ vroot, float* __restrict__ cb3) {

    const int t = threadIdx.x;
    const int blk = blockIdx.x;

    if (blk < NB_PART) {
        __shared__ int lhist[NBUCK], lbase[NBUCK], gbase[NBUCK], lcur[NBUCK];
        __shared__ int2 lrec[EPB];   // 8 KB
        for (int i = t; i < NBUCK; i += 256) lhist[i] = 0;
        __syncthreads();
        const int e0 = blk * EPB;
        const int tot = min(EPB, N_EDGES - e0);
        int mys[4], myd[4];
        float myw[4];
        for (int i = 0; i < 4; ++i) {
            int e = e0 + i * 256 + t;
            if (e < N_EDGES) {
                mys[i] = src[e];
                myd[i] = dst[e];
                myw[i] = ew[e];
                atomicAdd(&lhist[myd[i] >> 6], 1);
            } else {
                myd[i] = -1;
            }
        }
        __syncthreads();
        // local exclusive scan over bucket counts (one wave)
        if (t < 64) {
            int carry = 0;
            for (int c = 0; c < 5; ++c) {
                int idx = c * 64 + t;
                int v = (idx < NBUCK) ? lhist[idx] : 0;
                int xv = v;
                for (int s = 1; s < 64; s <<= 1) {
                    int u = __shfl_up(xv, s);
                    if (t >= s) xv += u;
                }
                if (idx < NBUCK) { lbase[idx] = carry + xv - v; lcur[idx] = 0; }
                carry += __shfl(xv, 63);
            }
        }
        __syncthreads();
        // reserve bucket ranges (gcursor[b] counts records; region = b*CAP)
        for (int i = t; i < NBUCK; i += 256) {
            int cnt = lhist[i];
            gbase[i] = cnt ? (i * CAP + atomicAdd(&gcursor[i], cnt)) : 0;
        }
        __syncthreads();
        // bucket-sort into LDS
        for (int i = 0; i < 4; ++i) {
            if (myd[i] >= 0) {
                int bb = myd[i] >> 6;
                int slot = lbase[bb] + atomicAdd(&lcur[bb], 1);
                lrec[slot] = make_int2((myd[i] << 16) | mys[i], __float_as_int(myw[i]));
            }
        }
        __syncthreads();
        // coalesced write-out of bucket runs
        for (int i = t; i < tot; i += 256) {
            int2 rc = lrec[i];
            int bb = ((unsigned)rc.x >> 16) >> 6;
            part[gbase[bb] + (i - lbase[bb])] = rc;
        }
    } else if (blk < NB_PART + NB_WCONV) {
        const int b = blk - NB_PART;
        for (int i = b * 256 + t; i < 256 * DIM; i += NB_WCONV * 256) {
            int n = i >> 7, k = i & 127;
            float v = (n < DIM) ? W1rel[n * DIM + k] : W1root[(n - DIM) * DIM + k];
            unsigned int h = bf16rne(v);
            wbh[i] = (unsigned short)h;
            wbl[i] = (unsigned short)bf16rne(v - __uint_as_float(h << 16));
        }
    } else {
        if (t < 64) {
            for (int kk = 0; kk < 2; ++kk) {
                int k = t + kk * 64;
                float sr = 0.f, so = 0.f;
                for (int h = 0; h < DIM; ++h) {
                    float wl = Wlin[h];
                    sr = fmaf(wl, W3rel[h * DIM + k], sr);
                    so = fmaf(wl, W3root[h * DIM + k], so);
                }
                vrel[k] = sr;
                vroot[k] = so;
            }
            float c = b3[t] * Wlin[t] + b3[t + 64] * Wlin[t + 64];
            for (int m = 32; m > 0; m >>= 1) c += __shfl_xor(c, m);
            if (t == 0) cb3[0] = c;
        }
    }
}

// ---------------------------------------------------------------------------
// K2: fused [in-place bucket counting-sort -> off/nend | split-bf16 MFMA GEMM]
// Both depend only on K1. LDS union 32 KB -> 4 blocks/CU.
// ---------------------------------------------------------------------------
union SMem2 {
    struct { int2 lrec[CAP]; int nh[64], ncur[64]; } s;       // 20992 B
    struct { unsigned short h[64 * DIM], l[64 * DIM]; } g;    // 32768 B
};

__global__ __launch_bounds__(256) void k_sort_gemm(
    const int* __restrict__ gcursor, int2* __restrict__ part,
    int* __restrict__ off, int* __restrict__ nend,
    const float* __restrict__ x,
    const unsigned short* __restrict__ wbh, const unsigned short* __restrict__ wbl,
    const float* __restrict__ b1,
    unsigned short* __restrict__ yb, float* __restrict__ r) {
    __shared__ SMem2 sm;
    const int t = threadIdx.x;

    if (blockIdx.x < NBUCK) {
        // ---------------- bucketsort (in place) ----------------
        const int b = blockIdx.x;
        const int base = b * CAP;
        const int cnt = gcursor[b];
        for (int i = t; i < cnt; i += 256) sm.s.lrec[i] = part[base + i];
        if (t < 64) sm.s.nh[t] = 0;
        __syncthreads();
        for (int i = t; i < cnt; i += 256)
            atomicAdd(&sm.s.nh[((unsigned)sm.s.lrec[i].x >> 16) & 63], 1);
        __syncthreads();
        if (t < 64) {
            int v = sm.s.nh[t];
            int xv = v;
            for (int s = 1; s < 64; s <<= 1) {
                int u = __shfl_up(xv, s);
                if (t >= s) xv += u;
            }
            int excl = xv - v;
            sm.s.ncur[t] = excl;
            int node = b * 64 + t;
            if (node < N_NODES) {
                off[node] = base + excl;
                nend[node] = base + excl + v;
            }
        }
        __syncthreads();
        for (int i = t; i < cnt; i += 256) {
            int2 rc = sm.s.lrec[i];
            int dl = ((unsigned)rc.x >> 16) & 63;
            int p = atomicAdd(&sm.s.ncur[dl], 1);
            part[base + p] = make_int2(rc.x & 0xFFFF, rc.y);
        }
    } else {
        // ---------------- GEMM 64-row x 64-col tile ----------------
        const int tile = blockIdx.x - NBUCK;
        const int g = tile >> 2;
        const int col0 = (tile & 3) * 64;
        uint4* sh = (uint4*)sm.g.h;
        uint4* sl = (uint4*)sm.g.l;
        const uint4* gh = (const uint4*)wbh + (size_t)col0 * 16;
        const uint4* gl = (const uint4*)wbl + (size_t)col0 * 16;
        for (int i = t; i < 1024; i += 256) {
            int row = i >> 4, c = i & 15;
            int sc = row * 16 + (c ^ (row & 15));
            sh[sc] = gh[i];
            sl[sc] = gl[i];
        }
        __syncthreads();

        const int lane = t & 63;
        const int m = lane & 15;
        const int q = lane >> 4;
        const int row0 = g * 64 + (t >> 6) * 16;
        const int row = row0 + m;
        const bool ok = row < N_NODES;
        const short8* SH = (const short8*)sm.g.h;
        const short8* SL = (const short8*)sm.g.l;

        floatx4 acc[4];
        #pragma unroll
        for (int i = 0; i < 4; ++i) acc[i] = (floatx4)(0.f);

        #pragma unroll
        for (int kc = 0; kc < 4; ++kc) {
            float4 v0 = make_float4(0.f, 0.f, 0.f, 0.f);
            float4 v1 = make_float4(0.f, 0.f, 0.f, 0.f);
            if (ok) {
                const float4* xp = (const float4*)(x + (size_t)row * DIM + kc * 32 + q * 8);
                v0 = xp[0];
                v1 = xp[1];
            }
            float f[8] = {v0.x, v0.y, v0.z, v0.w, v1.x, v1.y, v1.z, v1.w};
            short8 ah, al;
            #pragma unroll
            for (int i = 0; i < 8; ++i) {
                unsigned int h = bf16rne(f[i]);
                ah[i] = (short)h;
                al[i] = (short)bf16rne(f[i] - __uint_as_float(h << 16));
            }
            #pragma unroll
            for (int nt = 0; nt < 4; ++nt) {
                int nl = nt * 16 + m;
                int cc = (kc * 4 + q) ^ m;
                short8 bh = SH[nl * 16 + cc];
                short8 bl = SL[nl * 16 + cc];
                acc[nt] = __builtin_amdgcn_mfma_f32_16x16x32_bf16(ah, bh, acc[nt], 0, 0, 0);
                acc[nt] = __builtin_amdgcn_mfma_f32_16x16x32_bf16(al, bh, acc[nt], 0, 0, 0);
                acc[nt] = __builtin_amdgcn_mfma_f32_16x16x32_bf16(ah, bl, acc[nt], 0, 0, 0);
            }
        }

        // epilogue: C/D layout col=lane&15, row=q*4+reg
        #pragma unroll
        for (int nt = 0; nt < 4; ++nt) {
            int col = col0 + nt * 16 + m;
            float bias = (col >= DIM) ? b1[col - DIM] : 0.f;
            #pragma unroll
            for (int reg = 0; reg < 4; ++reg) {
                int orow = row0 + q * 4 + reg;
                if (orow < N_NODES) {
                    float v = acc[nt][reg];
                    if (col < DIM)
                        yb[orow * DIM + col] = (unsigned short)bf16rne(v);
                    else
                        r[orow * DIM + (col - DIM)] = v + bias;
                }
            }
        }
    }
}

// ---------------------------------------------------------------------------
// K3: agg — wave per node; 8 y-gathers in flight; h1=relu(agg+r); a,b dots
// ---------------------------------------------------------------------------
__global__ __launch_bounds__(256) void k_agg(const unsigned int* __restrict__ yb,
                                             const float2* __restrict__ r2,
                                             const int* __restrict__ off,
                                             const int* __restrict__ nend,
                                             const int2* __restrict__ grec,
                                             const float2* __restrict__ vrel2,
                                             const float2* __restrict__ vroot2,
                                             float* __restrict__ aout,
                                             float* __restrict__ bout) {
    const int lane = threadIdx.x & 63;
    const int node = blockIdx.x * 4 + (threadIdx.x >> 6);
    if (node >= N_NODES) return;

    int j = off[node];
    const int e1 = nend[node];
    float sx = 0.f, sy = 0.f;
    for (; j + 8 <= e1; j += 8) {
        int2 rc[8];
        #pragma unroll
        for (int u = 0; u < 8; ++u) rc[u] = grec[j + u];
        unsigned int v[8];
        #pragma unroll
        for (int u = 0; u < 8; ++u) v[u] = yb[rc[u].x * 64 + lane];
        #pragma unroll
        for (int u = 0; u < 8; ++u) {
            float w = __int_as_float(rc[u].y);
            sx = fmaf(w, __uint_as_float(v[u] << 16), sx);
            sy = fmaf(w, __uint_as_float(v[u] & 0xFFFF0000u), sy);
        }
    }
    for (; j < e1; ++j) {
        int2 rcs = grec[j];
        float w = __int_as_float(rcs.y);
        unsigned int vv = yb[rcs.x * 64 + lane];
        sx = fmaf(w, __uint_as_float(vv << 16), sx);
        sy = fmaf(w, __uint_as_float(vv & 0xFFFF0000u), sy);
    }
    float2 rr = r2[(size_t)node * 64 + lane];
    float hx = fmaxf(sx + rr.x, 0.f);
    float hy = fmaxf(sy + rr.y, 0.f);
    float2 vr = vrel2[lane];
    float2 vo = vroot2[lane];
    float pa = hx * vr.x + hy * vr.y;
    float pb = hx * vo.x + hy * vo.y;
    for (int mm = 32; mm > 0; mm >>= 1) {
        pa += __shfl_xor(pa, mm);
        pb += __shfl_xor(pb, mm);
    }
    if (lane == 0) {
        aout[node] = pa;
        bout[node] = pb;
    }
}

// ---------------------------------------------------------------------------
// K4: reduce + final — wave per node; bin by graph; spread partials; last
// block computes out[]
// ---------------------------------------------------------------------------
__global__ __launch_bounds__(256) void k_reduce_final(
    const int2* __restrict__ grec, const int* __restrict__ off,
    const int* __restrict__ nend,
    const float* __restrict__ a, const float* __restrict__ bvec,
    const int* __restrict__ batch,
    float* __restrict__ gpart, int* __restrict__ gpartc,
    int* __restrict__ ticket_red,
    const float* __restrict__ cb3, const float* __restrict__ blin,
    float* __restrict__ out) {
    __shared__ float sbin[NGRAPH];
    __shared__ int cbin[NGRAPH];
    __shared__ int islast;
    const int t = threadIdx.x;
    for (int i = t; i < NGRAPH; i += 256) { sbin[i] = 0.f; cbin[i] = 0; }
    __syncthreads();
    const int lane = t & 63;
    const int gw = blockIdx.x * 4 + (t >> 6);
    const int nw = gridDim.x * 4;
    for (int node = gw; node < N_NODES; node += nw) {
        const int e0 = off[node], e1 = nend[node];
        float s = 0.f;
        for (int j = e0 + lane; j < e1; j += 64) {
            int2 rc = grec[j];
            s = fmaf(__int_as_float(rc.y), a[rc.x], s);
        }
        for (int mm = 32; mm > 0; mm >>= 1) s += __shfl_xor(s, mm);
        if (lane == 0) {
            int g = batch[node];
            atomicAdd(&sbin[g], s + bvec[node]);
            atomicAdd(&cbin[g], 1);
        }
    }
    __syncthreads();
    const int slot = blockIdx.x & 63;
    for (int i = t; i < NGRAPH; i += 256) {
        atomicAdd(&gpart[slot * NGRAPH + i], sbin[i]);
        if (cbin[i]) atomicAdd(&gpartc[slot * NGRAPH + i], cbin[i]);
    }
    __syncthreads();
    if (t == 0) {
        __threadfence();
        islast = (atomicAdd(ticket_red, 1) == (int)gridDim.x - 1);
    }
    __syncthreads();
    if (islast) {
        __threadfence();
        if (t < NGRAPH) {
            float S = 0.f;
            int C = 0;
            for (int s2 = 0; s2 < 64; ++s2) {
                S += __hip_atomic_load(&gpart[s2 * NGRAPH + t], __ATOMIC_RELAXED,
                                       __HIP_MEMORY_SCOPE_AGENT);
                C += __hip_atomic_load(&gpartc[s2 * NGRAPH + t], __ATOMIC_RELAXED,
                                       __HIP_MEMORY_SCOPE_AGENT);
            }
            float denom = (C > 0) ? (float)C : 1.f;
            float v = (S + (float)C * cb3[0]) / denom + blin[0];
            out[t] = (v > 0.f) ? v : 0.f;
        }
    }
}

// ---------------------------------------------------------------------------
extern "C" void kernel_launch(void* const* d_in, const int* in_sizes, int n_in,
                              void* d_out, int out_size, void* d_ws, size_t ws_size,
                              hipStream_t stream) {
    const float* x = (const float*)d_in[0];
    const int* edge_index = (const int*)d_in[1];
    const int* src = edge_index;
    const int* dst = edge_index + N_EDGES;
    const int* batch = (const int*)d_in[2];
    const float* ew = (const float*)d_in[3];
    const float* W1rel = (const float*)d_in[4];
    const float* b1 = (const float*)d_in[5];
    const float* W1root = (const float*)d_in[6];
    const float* W3rel = (const float*)d_in[7];
    const float* b3 = (const float*)d_in[8];
    const float* W3root = (const float*)d_in[9];
    const float* Wlin = (const float*)d_in[10];
    const float* blin = (const float*)d_in[11];
    float* out = (float*)d_out;

    char* w = (char*)d_ws;
    size_t o = 0;
    auto alloc = [&](size_t bytes) -> void* {
        void* p = w + o;
        o += bytes;
        o = (o + 255) & ~(size_t)255;
        return p;
    };
    // zero region: gcursor[313] | ticket_red | gpart[64*64] f32 | gpartc[64*64]
    char* zbase = (char*)alloc((NBUCK + 1) * 4 + 64 * NGRAPH * 4 * 2);
    int* gcursor = (int*)zbase;
    int* ticket_red = gcursor + NBUCK;
    float* gpart = (float*)(zbase + (NBUCK + 1) * 4);
    int* gpartc = (int*)(zbase + (NBUCK + 1) * 4 + 64 * NGRAPH * 4);
    const size_t zbytes = (NBUCK + 1) * 4 + 64 * NGRAPH * 4 * 2;

    unsigned short* wbh = (unsigned short*)alloc((size_t)256 * DIM * 2);
    unsigned short* wbl = (unsigned short*)alloc((size_t)256 * DIM * 2);
    unsigned short* yb = (unsigned short*)alloc((size_t)N_NODES * DIM * 2);
    float* r = (float*)alloc((size_t)N_NODES * DIM * 4);
    int2* part = (int2*)alloc((size_t)NBUCK * CAP * 8);   // 6.4 MB padded
    int* off = (int*)alloc((size_t)N_NODES * 4);
    int* nend = (int*)alloc((size_t)N_NODES * 4);
    float* a = (float*)alloc((size_t)N_NODES * 4);
    float* b = (float*)alloc((size_t)N_NODES * 4);
    float* vrel = (float*)alloc(DIM * 4);
    float* vroot = (float*)alloc(DIM * 4);
    float* cb3 = (float*)alloc(4);

    hipMemsetAsync(zbase, 0, zbytes, stream);

    k_part_prep<<<NB_PART + NB_WCONV + 1, 256, 0, stream>>>(
        src, dst, ew, W1rel, W1root, W3rel, W3root, b3, Wlin,
        gcursor, part, wbh, wbl, vrel, vroot, cb3);

    k_sort_gemm<<<NBUCK + NB_GEMM, 256, 0, stream>>>(
        gcursor, part, off, nend, x, wbh, wbl, b1, yb, r);

    k_agg<<<(N_NODES + 3) / 4, 256, 0, stream>>>(
        (const unsigned int*)yb, (const float2*)r, off, nend, part,
        (const float2*)vrel, (const float2*)vroot, a, b);

    k_reduce_final<<<RED_BLOCKS, 256, 0, stream>>>(
        part, off, nend, a, b, batch, gpart, gpartc, ticket_red, cb3, blin, out);
}